// Round 2
// baseline (5843.140 us; speedup 1.0000x reference)
//
#include <hip/hip_runtime.h>
#include <stdint.h>

// N=4096, B=32, LATENT=16, UNITS=64, NNZ=65536, K=2, M=5.
#define NN    4096
#define BB    32
#define NNZE  65536
#define WA    512      // LATENT*B  (pass-A diffusion width)
#define WB    2048     // UNITS*B   (pass-B diffusion width)

// ---------- bf16 helpers ----------
__device__ __forceinline__ float bf2f(unsigned int h) {
    union { unsigned int u; float f; } c; c.u = h << 16; return c.f;
}
__device__ __forceinline__ unsigned int f2bf(float f) {
    union { float ff; unsigned int u; } c; c.ff = f;
    return (c.u + 0x7fffu + ((c.u >> 16) & 1u)) >> 16;
}

// ---------- CSR build (both supports per launch) ----------
__global__ void hist2_kernel(const int* __restrict__ r1, const int* __restrict__ r2,
                             int* __restrict__ cnt1, int* __restrict__ cnt2) {
    int e = blockIdx.x * blockDim.x + threadIdx.x;   // < 2*NNZE
    if (e < NNZE) atomicAdd(&cnt1[r1[e]], 1);
    else          atomicAdd(&cnt2[r2[e - NNZE]], 1);
}

// 4096-entry exclusive scan per block; block 0 -> support1, block 1 -> support2.
// cnt aliases cur (in-place rewrite to row starts).
__global__ void scan2_kernel(int* cur1, int* rp1, int* cur2, int* rp2) {
    int* cur = (blockIdx.x == 0) ? cur1 : cur2;
    int* rp  = (blockIdx.x == 0) ? rp1  : rp2;
    __shared__ int part[256];
    int t = threadIdx.x;
    int base = t * 16;
    int loc[16];
    int s = 0;
#pragma unroll
    for (int i = 0; i < 16; ++i) { loc[i] = s; s += cur[base + i]; }
    part[t] = s;
    __syncthreads();
    for (int off = 1; off < 256; off <<= 1) {
        int v = 0;
        if (t >= off) v = part[t - off];
        __syncthreads();
        part[t] += v;
        __syncthreads();
    }
    int excl = (t == 0) ? 0 : part[t - 1];
#pragma unroll
    for (int i = 0; i < 16; ++i) {
        int v = excl + loc[i];
        rp[base + i] = v;
    }
    __syncthreads();
#pragma unroll
    for (int i = 0; i < 16; ++i) cur[base + i] = rp[base + i];
    if (t == 255) rp[4096] = part[255];
}

__global__ void scatter2_kernel(const int* __restrict__ r1, const int* __restrict__ r2,
                                int* __restrict__ cur1, int* __restrict__ cur2,
                                int* __restrict__ perm1, int* __restrict__ perm2) {
    int e = blockIdx.x * blockDim.x + threadIdx.x;
    if (e < NNZE) {
        int pos = atomicAdd(&cur1[r1[e]], 1);
        perm1[pos] = e;
    } else {
        int ee = e - NNZE;
        int pos = atomicAdd(&cur2[r2[ee]], 1);
        perm2[pos] = ee;
    }
}

// ---------- pass A: x0[n, f*32+b] = y[b, n*16+f] ----------
__global__ void transposeA_kernel(const float* __restrict__ y, float* __restrict__ x0) {
    int idx = blockIdx.x * blockDim.x + threadIdx.x;   // < N*512
    int n = idx >> 9;
    int rem = idx & 511;
    int f = rem >> 5;
    int b = rem & 31;
    x0[idx] = y[b * (NN * 16) + n * 16 + f];
}

// xout[row,:] = alpha * (S @ xin)[row,:] + beta * xprev[row,:]   (width 512 f32)
__global__ void spmmA_kernel(const float* __restrict__ xin, const float* xprev,
                             float* __restrict__ xout, const int* __restrict__ rp,
                             const int* __restrict__ perm, const int* __restrict__ cols,
                             const float* __restrict__ vals, float alpha, float beta) {
    __shared__ int scol[128];
    __shared__ float sval[128];
    int row = blockIdx.x;
    int t = threadIdx.x;   // 128 threads, 4 cols each (float4)
    int beg = rp[row], end = rp[row + 1];
    float4 acc = make_float4(0.f, 0.f, 0.f, 0.f);
    for (int i0 = beg; i0 < end; i0 += 128) {
        int nn = end - i0; if (nn > 128) nn = 128;
        if (t < nn) { int e = perm[i0 + t]; scol[t] = cols[e]; sval[t] = vals[e]; }
        __syncthreads();
        for (int j = 0; j < nn; ++j) {
            const float4* xr = (const float4*)(xin + (size_t)scol[j] * WA);
            float4 xv = xr[t];
            float v = sval[j];
            acc.x += v * xv.x; acc.y += v * xv.y; acc.z += v * xv.z; acc.w += v * xv.w;
        }
        __syncthreads();
    }
    float4 res;
    res.x = alpha * acc.x; res.y = alpha * acc.y; res.z = alpha * acc.z; res.w = alpha * acc.w;
    if (beta != 0.0f) {
        float4 pv = ((const float4*)(xprev + (size_t)row * WA))[t];
        res.x += beta * pv.x; res.y += beta * pv.y; res.z += beta * pv.z; res.w += beta * pv.w;
    }
    ((float4*)(xout + (size_t)row * WA))[t] = res;
}

// fusedA: theta_sig[bn,u] = sigmoid(sum_m sum_f x_m[n,f,b]*Wt[f*5+m][u] + b_lat[u])
//         xB0[n, f*32+b]  = bf16(tanh(sum over Whid + b_hid[f]))
__global__ void fusedA_kernel(const float* __restrict__ x0, const float* __restrict__ x1,
                              const float* __restrict__ x2, const float* __restrict__ x3,
                              const float* __restrict__ x4,
                              const float* __restrict__ Wtheta, const float* __restrict__ Whid,
                              const float* __restrict__ b_lat, const float* __restrict__ b_hid,
                              float* __restrict__ theta_sig, unsigned short* __restrict__ xB0) {
    __shared__ float sWt[80 * 16];   // linear copy of Wtheta
    __shared__ float sWh[80 * 64];   // linear copy of Whid
    __shared__ float sBl[16];
    __shared__ float sBh[64];
    int t = threadIdx.x;   // 128
    for (int i = t; i < 80 * 16; i += 128) sWt[i] = Wtheta[i];
    for (int i = t; i < 80 * 64; i += 128) sWh[i] = Whid[i];
    if (t < 16) sBl[t] = b_lat[t];
    if (t < 64) sBh[t] = b_hid[t];
    __syncthreads();
    int b = t & 31, nl = t >> 5;
    int n = blockIdx.x * 4 + nl;
    float tacc[16];
    float hacc[64];
#pragma unroll
    for (int u = 0; u < 16; ++u) tacc[u] = 0.f;
#pragma unroll
    for (int u = 0; u < 64; ++u) hacc[u] = 0.f;
    const float* xs[5] = { x0, x1, x2, x3, x4 };
#pragma unroll
    for (int m = 0; m < 5; ++m) {
        const float* xp = xs[m] + (size_t)n * WA + b;
        float xv[16];
#pragma unroll
        for (int f = 0; f < 16; ++f) xv[f] = xp[f * 32];
#pragma unroll
        for (int f = 0; f < 16; ++f) {
            float xf = xv[f];
            const float* wt = &sWt[(f * 5 + m) * 16];
#pragma unroll
            for (int u = 0; u < 16; ++u) tacc[u] += xf * wt[u];
            const float* wh = &sWh[(f * 5 + m) * 64];
#pragma unroll
            for (int u = 0; u < 64; ++u) hacc[u] += xf * wh[u];
        }
    }
    // theta: sigmoid, stored f32 [b*N*16 + n*16 + u]
    size_t bn = (size_t)b * NN + n;
    float4* tp = (float4*)(theta_sig + bn * 16);
#pragma unroll
    for (int g = 0; g < 4; ++g) {
        float4 v;
        v.x = 1.0f / (1.0f + expf(-(tacc[g * 4 + 0] + sBl[g * 4 + 0])));
        v.y = 1.0f / (1.0f + expf(-(tacc[g * 4 + 1] + sBl[g * 4 + 1])));
        v.z = 1.0f / (1.0f + expf(-(tacc[g * 4 + 2] + sBl[g * 4 + 2])));
        v.w = 1.0f / (1.0f + expf(-(tacc[g * 4 + 3] + sBl[g * 4 + 3])));
        tp[g] = v;
    }
    // hid: tanh -> bf16, layout [n, f*32+b]
    unsigned short* hp = xB0 + (size_t)n * WB + b;
#pragma unroll
    for (int f = 0; f < 64; ++f)
        hp[f * 32] = (unsigned short)f2bf(tanhf(hacc[f] + sBh[f]));
}

// bf16 SpMM, width 2048: xout = alpha * (S @ xin) + beta * xprev
__global__ void spmmB_kernel(const unsigned short* __restrict__ xin, const unsigned short* xprev,
                             unsigned short* __restrict__ xout, const int* __restrict__ rp,
                             const int* __restrict__ perm, const int* __restrict__ cols,
                             const float* __restrict__ vals, float alpha, float beta) {
    __shared__ int scol[256];
    __shared__ float sval[256];
    int row = blockIdx.x;
    int t = threadIdx.x;   // 256 threads, 8 bf16 cols each (uint4)
    int beg = rp[row], end = rp[row + 1];
    float acc[8];
#pragma unroll
    for (int k = 0; k < 8; ++k) acc[k] = 0.f;
    for (int i0 = beg; i0 < end; i0 += 256) {
        int nn = end - i0; if (nn > 256) nn = 256;
        if (t < nn) { int e = perm[i0 + t]; scol[t] = cols[e]; sval[t] = vals[e]; }
        __syncthreads();
        for (int j = 0; j < nn; ++j) {
            const uint4* xr = (const uint4*)(xin + (size_t)scol[j] * WB);
            uint4 xv = xr[t];
            float v = sval[j];
            acc[0] += v * bf2f(xv.x & 0xffffu);
            acc[1] += v * bf2f(xv.x >> 16);
            acc[2] += v * bf2f(xv.y & 0xffffu);
            acc[3] += v * bf2f(xv.y >> 16);
            acc[4] += v * bf2f(xv.z & 0xffffu);
            acc[5] += v * bf2f(xv.z >> 16);
            acc[6] += v * bf2f(xv.w & 0xffffu);
            acc[7] += v * bf2f(xv.w >> 16);
        }
        __syncthreads();
    }
    float r[8];
#pragma unroll
    for (int k = 0; k < 8; ++k) r[k] = alpha * acc[k];
    if (beta != 0.0f) {
        uint4 pv = ((const uint4*)(xprev + (size_t)row * WB))[t];
        r[0] += beta * bf2f(pv.x & 0xffffu);
        r[1] += beta * bf2f(pv.x >> 16);
        r[2] += beta * bf2f(pv.y & 0xffffu);
        r[3] += beta * bf2f(pv.y >> 16);
        r[4] += beta * bf2f(pv.z & 0xffffu);
        r[5] += beta * bf2f(pv.z >> 16);
        r[6] += beta * bf2f(pv.w & 0xffffu);
        r[7] += beta * bf2f(pv.w >> 16);
    }
    uint4 o;
    o.x = f2bf(r[0]) | (f2bf(r[1]) << 16);
    o.y = f2bf(r[2]) | (f2bf(r[3]) << 16);
    o.z = f2bf(r[4]) | (f2bf(r[5]) << 16);
    o.w = f2bf(r[6]) | (f2bf(r[7]) << 16);
    ((uint4*)(xout + (size_t)row * WB))[t] = o;
}

// fusedB: out[b, n*16+u] = -theta_sig[bn,u] * tanh(sum_m sum_f x_m[n,f,b]*Wo[f*5+m][u] + b_lat[u])
__global__ void fusedB_kernel(const unsigned short* __restrict__ x0, const unsigned short* __restrict__ x1,
                              const unsigned short* __restrict__ x2, const unsigned short* __restrict__ x3,
                              const unsigned short* __restrict__ x4,
                              const float* __restrict__ Wout, const float* __restrict__ b_lat,
                              const float* __restrict__ theta_sig, float* __restrict__ out) {
    __shared__ float sWo[320 * 16];   // linear copy of Wout (UNITS*M x LATENT)
    __shared__ float sBl[16];
    int t = threadIdx.x;   // 128
    for (int i = t; i < 320 * 16; i += 128) sWo[i] = Wout[i];
    if (t < 16) sBl[t] = b_lat[t];
    __syncthreads();
    int b = t & 31, nl = t >> 5;
    int n = blockIdx.x * 4 + nl;
    float acc[16];
#pragma unroll
    for (int u = 0; u < 16; ++u) acc[u] = 0.f;
    const unsigned short* xs[5] = { x0, x1, x2, x3, x4 };
#pragma unroll
    for (int m = 0; m < 5; ++m) {
        const unsigned short* xp = xs[m] + (size_t)n * WB + b;
#pragma unroll
        for (int f = 0; f < 64; ++f) {
            float xf = bf2f((unsigned int)xp[f * 32]);
            const float* wo = &sWo[(f * 5 + m) * 16];
#pragma unroll
            for (int u = 0; u < 16; ++u) acc[u] += xf * wo[u];
        }
    }
    size_t bn = (size_t)b * NN + n;
    const float4* tp = (const float4*)(theta_sig + bn * 16);
    float4* op = (float4*)(out + bn * 16);
#pragma unroll
    for (int g = 0; g < 4; ++g) {
        float4 th = tp[g];
        float4 v;
        v.x = -th.x * tanhf(acc[g * 4 + 0] + sBl[g * 4 + 0]);
        v.y = -th.y * tanhf(acc[g * 4 + 1] + sBl[g * 4 + 1]);
        v.z = -th.z * tanhf(acc[g * 4 + 2] + sBl[g * 4 + 2]);
        v.w = -th.w * tanhf(acc[g * 4 + 3] + sBl[g * 4 + 3]);
        op[g] = v;
    }
}

extern "C" void kernel_launch(void* const* d_in, const int* in_sizes, int n_in,
                              void* d_out, int out_size, void* d_ws, size_t ws_size,
                              hipStream_t stream) {
    const float* y      = (const float*)d_in[1];
    const float* Wtheta = (const float*)d_in[2];
    const float* b_lat  = (const float*)d_in[3];
    const float* Whid   = (const float*)d_in[4];
    const float* b_hid  = (const float*)d_in[5];
    const float* Wout   = (const float*)d_in[6];
    const int*   r1     = (const int*)d_in[7];
    const int*   c1     = (const int*)d_in[8];
    const float* v1     = (const float*)d_in[9];
    const int*   r2     = (const int*)d_in[10];
    const int*   c2     = (const int*)d_in[11];
    const float* v2     = (const float*)d_in[12];
    float* out = (float*)d_out;

    // ---- workspace layout ----
    char* ws = (char*)d_ws;
    size_t off = 0;
    auto alloc = [&](size_t bytes) -> char* {
        char* p = ws + off;
        off += (bytes + 255) & ~(size_t)255;
        return p;
    };
    int* rp1   = (int*)alloc(4097 * 4);
    int* rp2   = (int*)alloc(4097 * 4);
    int* cur1  = (int*)alloc(4096 * 4);      // doubles as count buffer; cur2 contiguous
    int* cur2  = (int*)alloc(4096 * 4);
    int* perm1 = (int*)alloc(NNZE * 4);
    int* perm2 = (int*)alloc(NNZE * 4);
    float* theta_sig = (float*)alloc((size_t)BB * NN * 16 * 4);        // 8 MB
    unsigned short* xB0 = (unsigned short*)alloc((size_t)NN * WB * 2); // 16 MB
    char* bigR = alloc((size_t)64 * 1024 * 1024);                      // 64 MB shared region
    // pass A states (8 MB each) in bigR[0..40MB)
    float* xA0 = (float*)(bigR + 0 * (size_t)NN * WA * 4);
    float* xA1 = (float*)(bigR + 1 * (size_t)NN * WA * 4);
    float* xA2 = (float*)(bigR + 2 * (size_t)NN * WA * 4);
    float* xA3 = (float*)(bigR + 3 * (size_t)NN * WA * 4);
    float* xA4 = (float*)(bigR + 4 * (size_t)NN * WA * 4);
    // pass B states (16 MB each) reuse bigR after pass A is consumed
    unsigned short* xB1 = (unsigned short*)(bigR + 0 * (size_t)NN * WB * 2);
    unsigned short* xB2 = (unsigned short*)(bigR + 1 * (size_t)NN * WB * 2);
    unsigned short* xB3 = (unsigned short*)(bigR + 2 * (size_t)NN * WB * 2);
    unsigned short* xB4 = (unsigned short*)(bigR + 3 * (size_t)NN * WB * 2);
    if (off > ws_size) return;   // fail loudly (wrong output) if ws too small

    // ---- CSR build for both supports ----
    hipMemsetAsync(cur1, 0, 2 * 4096 * 4, stream);   // cur1+cur2 contiguous
    hist2_kernel<<<2 * NNZE / 256, 256, 0, stream>>>(r1, r2, cur1, cur2);
    scan2_kernel<<<2, 256, 0, stream>>>(cur1, rp1, cur2, rp2);
    scatter2_kernel<<<2 * NNZE / 256, 256, 0, stream>>>(r1, r2, cur1, cur2, perm1, perm2);

    // ---- pass A: F=16 diffusion, keep all 5 states ----
    transposeA_kernel<<<(NN * WA) / 256, 256, 0, stream>>>(y, xA0);
    spmmA_kernel<<<NN, 128, 0, stream>>>(xA0, xA0, xA1, rp1, perm1, c1, v1, 1.f, 0.f);
    spmmA_kernel<<<NN, 128, 0, stream>>>(xA1, xA0, xA2, rp1, perm1, c1, v1, 2.f, -1.f);
    spmmA_kernel<<<NN, 128, 0, stream>>>(xA0, xA0, xA3, rp2, perm2, c2, v2, 1.f, 0.f);
    spmmA_kernel<<<NN, 128, 0, stream>>>(xA3, xA0, xA4, rp2, perm2, c2, v2, 2.f, -1.f);
    fusedA_kernel<<<NN / 4, 128, 0, stream>>>(xA0, xA1, xA2, xA3, xA4, Wtheta, Whid,
                                              b_lat, b_hid, theta_sig, xB0);

    // ---- pass B: F=64 diffusion (bf16), keep all 5 states ----
    spmmB_kernel<<<NN, 256, 0, stream>>>(xB0, xB0, xB1, rp1, perm1, c1, v1, 1.f, 0.f);
    spmmB_kernel<<<NN, 256, 0, stream>>>(xB1, xB0, xB2, rp1, perm1, c1, v1, 2.f, -1.f);
    spmmB_kernel<<<NN, 256, 0, stream>>>(xB0, xB0, xB3, rp2, perm2, c2, v2, 1.f, 0.f);
    spmmB_kernel<<<NN, 256, 0, stream>>>(xB3, xB0, xB4, rp2, perm2, c2, v2, 2.f, -1.f);
    fusedB_kernel<<<NN / 4, 128, 0, stream>>>(xB0, xB1, xB2, xB3, xB4, Wout, b_lat,
                                              theta_sig, out);
}

// Round 3
// 464.834 us; speedup vs baseline: 12.5704x; 12.5704x over previous
//
#include <hip/hip_runtime.h>
#include <stdint.h>

// N=4096, B=32, LATENT=16, UNITS=64, NNZ=65536, K=2, M=5.
#define NN    4096
#define BB    32
#define NNZE  65536
#define WA    512      // LATENT*B  (pass-A diffusion width)
#define WB    2048     // UNITS*B   (pass-B diffusion width)

// ---------- bf16 helpers ----------
__device__ __forceinline__ float bf2f(unsigned int h) {
    union { unsigned int u; float f; } c; c.u = h << 16; return c.f;
}
__device__ __forceinline__ unsigned int f2bf(float f) {
    union { float ff; unsigned int u; } c; c.ff = f;
    return (c.u + 0x7fffu + ((c.u >> 16) & 1u)) >> 16;
}

// ---------- CSR build (both supports per launch) ----------
__global__ void hist2_kernel(const int* __restrict__ r1, const int* __restrict__ r2,
                             int* __restrict__ cnt1, int* __restrict__ cnt2) {
    int e = blockIdx.x * blockDim.x + threadIdx.x;   // < 2*NNZE
    if (e < NNZE) atomicAdd(&cnt1[r1[e]], 1);
    else          atomicAdd(&cnt2[r2[e - NNZE]], 1);
}

__global__ void scan2_kernel(int* cur1, int* rp1, int* cur2, int* rp2) {
    int* cur = (blockIdx.x == 0) ? cur1 : cur2;
    int* rp  = (blockIdx.x == 0) ? rp1  : rp2;
    __shared__ int part[256];
    int t = threadIdx.x;
    int base = t * 16;
    int loc[16];
    int s = 0;
#pragma unroll
    for (int i = 0; i < 16; ++i) { loc[i] = s; s += cur[base + i]; }
    part[t] = s;
    __syncthreads();
    for (int off = 1; off < 256; off <<= 1) {
        int v = 0;
        if (t >= off) v = part[t - off];
        __syncthreads();
        part[t] += v;
        __syncthreads();
    }
    int excl = (t == 0) ? 0 : part[t - 1];
#pragma unroll
    for (int i = 0; i < 16; ++i) rp[base + i] = excl + loc[i];
    __syncthreads();
#pragma unroll
    for (int i = 0; i < 16; ++i) cur[base + i] = rp[base + i];
    if (t == 255) rp[4096] = part[255];
}

__global__ void scatter2_kernel(const int* __restrict__ r1, const int* __restrict__ r2,
                                int* __restrict__ cur1, int* __restrict__ cur2,
                                int* __restrict__ perm1, int* __restrict__ perm2) {
    int e = blockIdx.x * blockDim.x + threadIdx.x;
    if (e < NNZE) {
        int pos = atomicAdd(&cur1[r1[e]], 1);
        perm1[pos] = e;
    } else {
        int ee = e - NNZE;
        int pos = atomicAdd(&cur2[r2[ee]], 1);
        perm2[pos] = ee;
    }
}

// ---------- rowA0: transpose y into x0 row + m=0 projections (WRITE) ----------
// block = row n, 128 threads: b = t&31, q = t>>5 (0..3)
__global__ void rowA0_kernel(const float* __restrict__ y,
                             const float* __restrict__ Wtheta, const float* __restrict__ Whid,
                             float* __restrict__ x0, float* __restrict__ theta_acc,
                             float* __restrict__ hid_acc) {
    __shared__ float srow[WA];       // [f*32+b]
    __shared__ float sWt[16 * 16];   // m=0 slice
    __shared__ float sWh[16 * 64];
    int t = threadIdx.x;
    int n = blockIdx.x;
    for (int i = t; i < 256; i += 128) { int f = i >> 4, u = i & 15; sWt[i] = Wtheta[(f * 5) * 16 + u]; }
    for (int i = t; i < 1024; i += 128) { int f = i >> 6, u = i & 63; sWh[i] = Whid[(f * 5) * 64 + u]; }
    int b = t & 31, q = t >> 5;
    float4 y4 = *(const float4*)(y + (size_t)b * (NN * 16) + n * 16 + 4 * q);
    srow[(4 * q + 0) * 32 + b] = y4.x;
    srow[(4 * q + 1) * 32 + b] = y4.y;
    srow[(4 * q + 2) * 32 + b] = y4.z;
    srow[(4 * q + 3) * 32 + b] = y4.w;
    __syncthreads();
    ((float4*)(x0 + (size_t)n * WA))[t] = ((const float4*)srow)[t];
    float xv[16];
#pragma unroll
    for (int f = 0; f < 16; ++f) xv[f] = srow[f * 32 + b];
    float tac[4];
#pragma unroll
    for (int j = 0; j < 4; ++j) tac[j] = 0.f;
    float hac[16];
#pragma unroll
    for (int j = 0; j < 16; ++j) hac[j] = 0.f;
#pragma unroll
    for (int f = 0; f < 16; ++f) {
        float xf = xv[f];
#pragma unroll
        for (int j = 0; j < 4; ++j) tac[j] += xf * sWt[f * 16 + 4 * q + j];
#pragma unroll
        for (int j = 0; j < 16; ++j) hac[j] += xf * sWh[f * 64 + 16 * q + j];
    }
    *(float4*)(theta_acc + ((size_t)b * NN + n) * 16 + 4 * q) =
        make_float4(tac[0], tac[1], tac[2], tac[3]);
    float* hp = hid_acc + (size_t)n * WB + b;
#pragma unroll
    for (int j = 0; j < 16; ++j) hp[(16 * q + j) * 32] = hac[j];
}

// ---------- spmmA + projection epilogue (RMW into theta/hid) ----------
// xout[row,:] = alpha*(S@xin)[row,:] + beta*xprev[row,:]; then project with m-slice.
__global__ void spmmA_proj_kernel(const float* __restrict__ xin, const float* xprev,
                                  float* __restrict__ xout, const int* __restrict__ rp,
                                  const int* __restrict__ perm, const int* __restrict__ cols,
                                  const float* __restrict__ vals,
                                  const float* __restrict__ Wtheta, const float* __restrict__ Whid,
                                  int m, float alpha, float beta,
                                  float* __restrict__ theta_acc, float* __restrict__ hid_acc) {
    __shared__ int scol[128];
    __shared__ float sval[128];
    __shared__ float srow[WA];
    __shared__ float sWt[16 * 16];
    __shared__ float sWh[16 * 64];
    int row = blockIdx.x;
    int t = threadIdx.x;   // 128 threads, 4 cols each (float4)
    for (int i = t; i < 256; i += 128) { int f = i >> 4, u = i & 15; sWt[i] = Wtheta[(f * 5 + m) * 16 + u]; }
    for (int i = t; i < 1024; i += 128) { int f = i >> 6, u = i & 63; sWh[i] = Whid[(f * 5 + m) * 64 + u]; }
    int beg = rp[row], end = rp[row + 1];
    float4 acc = make_float4(0.f, 0.f, 0.f, 0.f);
    for (int i0 = beg; i0 < end; i0 += 128) {
        int nn = end - i0; if (nn > 128) nn = 128;
        __syncthreads();
        if (t < nn) { int e = perm[i0 + t]; scol[t] = cols[e]; sval[t] = vals[e]; }
        __syncthreads();
        for (int j = 0; j < nn; ++j) {
            const float4* xr = (const float4*)(xin + (size_t)scol[j] * WA);
            float4 xv = xr[t];
            float v = sval[j];
            acc.x += v * xv.x; acc.y += v * xv.y; acc.z += v * xv.z; acc.w += v * xv.w;
        }
    }
    float4 res;
    res.x = alpha * acc.x; res.y = alpha * acc.y; res.z = alpha * acc.z; res.w = alpha * acc.w;
    if (beta != 0.0f) {
        float4 pv = ((const float4*)(xprev + (size_t)row * WA))[t];
        res.x += beta * pv.x; res.y += beta * pv.y; res.z += beta * pv.z; res.w += beta * pv.w;
    }
    ((float4*)(xout + (size_t)row * WA))[t] = res;
    __syncthreads();           // scol/sval reuse done; publish srow
    ((float4*)srow)[t] = res;
    __syncthreads();
    // projection: b = t&31, q = t>>5
    int b = t & 31, q = t >> 5;
    float xv[16];
#pragma unroll
    for (int f = 0; f < 16; ++f) xv[f] = srow[f * 32 + b];
    float tac[4];
#pragma unroll
    for (int j = 0; j < 4; ++j) tac[j] = 0.f;
    float hac[16];
#pragma unroll
    for (int j = 0; j < 16; ++j) hac[j] = 0.f;
#pragma unroll
    for (int f = 0; f < 16; ++f) {
        float xf = xv[f];
#pragma unroll
        for (int j = 0; j < 4; ++j) tac[j] += xf * sWt[f * 16 + 4 * q + j];
#pragma unroll
        for (int j = 0; j < 16; ++j) hac[j] += xf * sWh[f * 64 + 16 * q + j];
    }
    float4* tp = (float4*)(theta_acc + ((size_t)b * NN + row) * 16 + 4 * q);
    float4 tv = *tp;
    tv.x += tac[0]; tv.y += tac[1]; tv.z += tac[2]; tv.w += tac[3];
    *tp = tv;
    float* hp = hid_acc + (size_t)row * WB + b;
#pragma unroll
    for (int j = 0; j < 16; ++j) hp[(16 * q + j) * 32] += hac[j];
}

// ---------- rowB0: tanh(hid+b_hid) -> bf16 xB0 + m=0 Wout projection (WRITE) ----------
// block = row n, 256 threads
__global__ void rowB0_kernel(const float* __restrict__ hid_acc, const float* __restrict__ b_hid,
                             const float* __restrict__ Wout,
                             unsigned short* __restrict__ xB0, float* __restrict__ out_acc) {
    __shared__ float srow[WB];       // tanh values f32
    __shared__ float sWo[64 * 16];   // m=0 slice
    int t = threadIdx.x;
    int n = blockIdx.x;
    for (int i = t; i < 1024; i += 256) { int f = i >> 4, u = i & 15; sWo[i] = Wout[(f * 5) * 16 + u]; }
    const float4* hp = (const float4*)(hid_acc + (size_t)n * WB) + t * 2;
    float4 h0 = hp[0], h1 = hp[1];
    float v[8] = { h0.x, h0.y, h0.z, h0.w, h1.x, h1.y, h1.z, h1.w };
    int base = t * 8;
#pragma unroll
    for (int j = 0; j < 8; ++j) {
        int u = (base + j) >> 5;
        v[j] = tanhf(v[j] + b_hid[u]);
        srow[base + j] = v[j];
    }
    uint4 o;
    o.x = f2bf(v[0]) | (f2bf(v[1]) << 16);
    o.y = f2bf(v[2]) | (f2bf(v[3]) << 16);
    o.z = f2bf(v[4]) | (f2bf(v[5]) << 16);
    o.w = f2bf(v[6]) | (f2bf(v[7]) << 16);
    ((uint4*)(xB0 + (size_t)n * WB))[t] = o;
    __syncthreads();
    int b = t & 31, q = t >> 5;   // q 0..7
    float a0 = 0.f, a1 = 0.f;
#pragma unroll
    for (int up = 0; up < 64; ++up) {
        float xf = srow[up * 32 + b];
        a0 += xf * sWo[up * 16 + 2 * q];
        a1 += xf * sWo[up * 16 + 2 * q + 1];
    }
    float2* op = (float2*)(out_acc + ((size_t)b * NN + n) * 16 + 2 * q);
    *op = make_float2(a0, a1);
}

// ---------- spmmB (bf16 states) + Wout projection epilogue (RMW) ----------
__global__ void spmmB_proj_kernel(const unsigned short* __restrict__ xin, const unsigned short* xprev,
                                  unsigned short* __restrict__ xout, const int* __restrict__ rp,
                                  const int* __restrict__ perm, const int* __restrict__ cols,
                                  const float* __restrict__ vals,
                                  const float* __restrict__ Wout, int m, float alpha, float beta,
                                  float* __restrict__ out_acc) {
    __shared__ int scol[256];
    __shared__ float sval[256];
    __shared__ float srow[WB];
    __shared__ float sWo[64 * 16];
    int row = blockIdx.x;
    int t = threadIdx.x;   // 256 threads, 8 bf16 cols each (uint4)
    for (int i = t; i < 1024; i += 256) { int f = i >> 4, u = i & 15; sWo[i] = Wout[(f * 5 + m) * 16 + u]; }
    int beg = rp[row], end = rp[row + 1];
    float acc[8];
#pragma unroll
    for (int k = 0; k < 8; ++k) acc[k] = 0.f;
    for (int i0 = beg; i0 < end; i0 += 256) {
        int nn = end - i0; if (nn > 256) nn = 256;
        __syncthreads();
        if (t < nn) { int e = perm[i0 + t]; scol[t] = cols[e]; sval[t] = vals[e]; }
        __syncthreads();
        for (int j = 0; j < nn; ++j) {
            const uint4* xr = (const uint4*)(xin + (size_t)scol[j] * WB);
            uint4 xv = xr[t];
            float v = sval[j];
            acc[0] += v * bf2f(xv.x & 0xffffu);
            acc[1] += v * bf2f(xv.x >> 16);
            acc[2] += v * bf2f(xv.y & 0xffffu);
            acc[3] += v * bf2f(xv.y >> 16);
            acc[4] += v * bf2f(xv.z & 0xffffu);
            acc[5] += v * bf2f(xv.z >> 16);
            acc[6] += v * bf2f(xv.w & 0xffffu);
            acc[7] += v * bf2f(xv.w >> 16);
        }
    }
    float r[8];
#pragma unroll
    for (int k = 0; k < 8; ++k) r[k] = alpha * acc[k];
    if (beta != 0.0f) {
        uint4 pv = ((const uint4*)(xprev + (size_t)row * WB))[t];
        r[0] += beta * bf2f(pv.x & 0xffffu);
        r[1] += beta * bf2f(pv.x >> 16);
        r[2] += beta * bf2f(pv.y & 0xffffu);
        r[3] += beta * bf2f(pv.y >> 16);
        r[4] += beta * bf2f(pv.z & 0xffffu);
        r[5] += beta * bf2f(pv.z >> 16);
        r[6] += beta * bf2f(pv.w & 0xffffu);
        r[7] += beta * bf2f(pv.w >> 16);
    }
    uint4 o;
    o.x = f2bf(r[0]) | (f2bf(r[1]) << 16);
    o.y = f2bf(r[2]) | (f2bf(r[3]) << 16);
    o.z = f2bf(r[4]) | (f2bf(r[5]) << 16);
    o.w = f2bf(r[6]) | (f2bf(r[7]) << 16);
    ((uint4*)(xout + (size_t)row * WB))[t] = o;
    __syncthreads();          // scol/sval done; publish srow
    int base = t * 8;
#pragma unroll
    for (int j = 0; j < 8; ++j) srow[base + j] = r[j];
    __syncthreads();
    int b = t & 31, q = t >> 5;
    float a0 = 0.f, a1 = 0.f;
#pragma unroll
    for (int up = 0; up < 64; ++up) {
        float xf = srow[up * 32 + b];
        a0 += xf * sWo[up * 16 + 2 * q];
        a1 += xf * sWo[up * 16 + 2 * q + 1];
    }
    float2* op = (float2*)(out_acc + ((size_t)b * NN + row) * 16 + 2 * q);
    float2 cv = *op;
    cv.x += a0; cv.y += a1;
    *op = cv;
}

// out[i] = -sigmoid(theta_acc[i] + b_lat[u]) * tanh(out_acc[i] + b_lat[u])
__global__ void final_kernel(const float* __restrict__ theta_acc, const float* __restrict__ out_acc,
                             const float* __restrict__ b_lat, float* __restrict__ out) {
    int i = blockIdx.x * blockDim.x + threadIdx.x;   // < B*N*16
    float bl = b_lat[i & 15];
    float tv = theta_acc[i] + bl;
    float ov = out_acc[i] + bl;
    float sg = 1.0f / (1.0f + expf(-tv));
    out[i] = -sg * tanhf(ov);
}

extern "C" void kernel_launch(void* const* d_in, const int* in_sizes, int n_in,
                              void* d_out, int out_size, void* d_ws, size_t ws_size,
                              hipStream_t stream) {
    const float* y      = (const float*)d_in[1];
    const float* Wtheta = (const float*)d_in[2];
    const float* b_lat  = (const float*)d_in[3];
    const float* Whid   = (const float*)d_in[4];
    const float* b_hid  = (const float*)d_in[5];
    const float* Wout   = (const float*)d_in[6];
    const int*   r1     = (const int*)d_in[7];
    const int*   c1     = (const int*)d_in[8];
    const float* v1     = (const float*)d_in[9];
    const int*   r2     = (const int*)d_in[10];
    const int*   c2     = (const int*)d_in[11];
    const float* v2     = (const float*)d_in[12];
    float* out = (float*)d_out;

    // ---- workspace layout ----
    char* ws = (char*)d_ws;
    size_t off = 0;
    auto alloc = [&](size_t bytes) -> char* {
        char* p = ws + off;
        off += (bytes + 255) & ~(size_t)255;
        return p;
    };
    int* rp1   = (int*)alloc(4097 * 4);
    int* rp2   = (int*)alloc(4097 * 4);
    int* cur1  = (int*)alloc(4096 * 4);      // count buffer; cur2 contiguous after
    int* cur2  = (int*)alloc(4096 * 4);
    int* perm1 = (int*)alloc(NNZE * 4);
    int* perm2 = (int*)alloc(NNZE * 4);
    float* theta_acc = (float*)alloc((size_t)BB * NN * 16 * 4);          // 8 MB
    float* out_acc   = (float*)alloc((size_t)BB * NN * 16 * 4);          // 8 MB
    float* hid_acc   = (float*)alloc((size_t)NN * WB * 4);               // 32 MB
    float* xA0 = (float*)alloc((size_t)NN * WA * 4);                     // 8 MB
    float* xAp = (float*)alloc((size_t)NN * WA * 4);                     // 8 MB
    float* xAq = (float*)alloc((size_t)NN * WA * 4);                     // 8 MB
    unsigned short* xB0 = (unsigned short*)alloc((size_t)NN * WB * 2);   // 16 MB
    unsigned short* xBp = (unsigned short*)alloc((size_t)NN * WB * 2);   // 16 MB
    unsigned short* xBq = (unsigned short*)alloc((size_t)NN * WB * 2);   // 16 MB
    if (off > ws_size) return;   // fail loudly if ws too small

    // ---- CSR build ----
    hipMemsetAsync(cur1, 0, 2 * 4096 * 4, stream);   // cur1+cur2 contiguous
    hist2_kernel<<<2 * NNZE / 256, 256, 0, stream>>>(r1, r2, cur1, cur2);
    scan2_kernel<<<2, 256, 0, stream>>>(cur1, rp1, cur2, rp2);
    scatter2_kernel<<<2 * NNZE / 256, 256, 0, stream>>>(r1, r2, cur1, cur2, perm1, perm2);

    // ---- pass A: transpose + m=0 write, then 4 spmm+proj (RMW) ----
    rowA0_kernel<<<NN, 128, 0, stream>>>(y, Wtheta, Whid, xA0, theta_acc, hid_acc);
    spmmA_proj_kernel<<<NN, 128, 0, stream>>>(xA0, xA0, xAp, rp1, perm1, c1, v1,
                                              Wtheta, Whid, 1, 1.f, 0.f, theta_acc, hid_acc);
    spmmA_proj_kernel<<<NN, 128, 0, stream>>>(xAp, xA0, xAq, rp1, perm1, c1, v1,
                                              Wtheta, Whid, 2, 2.f, -1.f, theta_acc, hid_acc);
    spmmA_proj_kernel<<<NN, 128, 0, stream>>>(xA0, xA0, xAp, rp2, perm2, c2, v2,
                                              Wtheta, Whid, 3, 1.f, 0.f, theta_acc, hid_acc);
    spmmA_proj_kernel<<<NN, 128, 0, stream>>>(xAp, xA0, xAq, rp2, perm2, c2, v2,
                                              Wtheta, Whid, 4, 2.f, -1.f, theta_acc, hid_acc);

    // ---- pass B: activation + m=0 write, then 4 spmm+proj (RMW) ----
    rowB0_kernel<<<NN, 256, 0, stream>>>(hid_acc, b_hid, Wout, xB0, out_acc);
    spmmB_proj_kernel<<<NN, 256, 0, stream>>>(xB0, xB0, xBp, rp1, perm1, c1, v1,
                                              Wout, 1, 1.f, 0.f, out_acc);
    spmmB_proj_kernel<<<NN, 256, 0, stream>>>(xBp, xB0, xBq, rp1, perm1, c1, v1,
                                              Wout, 2, 2.f, -1.f, out_acc);
    spmmB_proj_kernel<<<NN, 256, 0, stream>>>(xB0, xB0, xBp, rp2, perm2, c2, v2,
                                              Wout, 3, 1.f, 0.f, out_acc);
    spmmB_proj_kernel<<<NN, 256, 0, stream>>>(xBp, xB0, xBq, rp2, perm2, c2, v2,
                                              Wout, 4, 2.f, -1.f, out_acc);

    // ---- epilogue ----
    final_kernel<<<(BB * NN * 16) / 256, 256, 0, stream>>>(theta_acc, out_acc, b_lat, out);
}